// Round 2
// baseline (394.855 us; speedup 1.0000x reference)
//
#include <hip/hip_runtime.h>
#include <hip/hip_bf16.h>
#include <math.h>

// ConcatMLPAggregator: gather-top8 + concat + MLP(1025->128 gelu ->128), bf16 MFMA.
//
// Inputs:
//  d_in[0] v         [8192,64,128] fp32
//  d_in[1] batch_idx [32768] int32
//  d_in[2] mask      [32768,64] bool -> passed as int32 (harness: integer -> const int*)
//  d_in[3] count     [32768] int32
//  d_in[4] W1        [1025,128] fp32
//  d_in[5] b1        [128] fp32
//  d_in[6] W2        [128,128] fp32
//  d_in[7] b2        [128] fp32
// Output: [32768,128] fp32

typedef __attribute__((ext_vector_type(8))) short bf16x8;
typedef __attribute__((ext_vector_type(4))) float f32x4;

#define NCHAINS 32768
#define LPOS    64
#define DV      128
#define HID     128
#define KDIM    1024   // 8 slots * 128
#define CPB     32     // chains per block

// round-to-nearest-even f32 -> bf16 (truncation would bias ~0.08, too close to threshold)
__device__ __forceinline__ unsigned short cvt_bf16(float a) {
  unsigned u = __float_as_uint(a);
  u += 0x7fffu + ((u >> 16) & 1u);
  return (unsigned short)(u >> 16);
}
__device__ __forceinline__ unsigned pk2_bf16(float a, float b) {
  unsigned ua = __float_as_uint(a), ub = __float_as_uint(b);
  ua += 0x7fffu + ((ua >> 16) & 1u);
  ub += 0x7fffu + ((ub >> 16) & 1u);
  return (ua >> 16) | (ub & 0xffff0000u);
}
__device__ __forceinline__ float gelu_exact(float x) {
  return 0.5f * x * (1.0f + erff(x * 0.70710678118654752f));
}

// Prep: W1t[n][k] = bf16(W1[k][n]) for k<1024; W2t[n][k] = bf16(W2[k][n]); zero row.
__global__ __launch_bounds__(256) void prep_kernel(
    const float* __restrict__ W1, const float* __restrict__ W2,
    unsigned short* __restrict__ W1t, unsigned short* __restrict__ W2t,
    float* __restrict__ zr) {
  int id = blockIdx.x * 256 + threadIdx.x;
  if (id < HID * KDIM) {
    int n = id >> 10, k = id & 1023;
    W1t[id] = cvt_bf16(W1[k * HID + n]);
  }
  if (id < HID * HID) {
    int n = id >> 7, k = id & 127;
    W2t[id] = cvt_bf16(W2[k * HID + n]);
  }
  if (id < DV) zr[id] = 0.0f;
}

__global__ __launch_bounds__(256, 2) void agg_mlp_kernel(
    const float* __restrict__ v, const int* __restrict__ batch_idx,
    const int* __restrict__ mask, const int* __restrict__ count,
    const float* __restrict__ W1, const float* __restrict__ b1,
    const float* __restrict__ W2, const float* __restrict__ b2,
    const unsigned short* __restrict__ W1t, const unsigned short* __restrict__ W2t,
    const float* __restrict__ zr, float* __restrict__ out) {
  __shared__ const float* s_ptr[CPB][8];
  __shared__ float s_logc[CPB];
  __shared__ unsigned short s_X[CPB][KDIM + 8];   // stride 1032 elems = 2064 B (bank-safe)
  __shared__ unsigned short s_H[CPB][HID + 8];    // stride 136 elems = 272 B

  const int tid = threadIdx.x;
  const int blk = blockIdx.x;

  // ---- Phase 0: per-chain first-8 set-element extraction -> row pointers ----
  // mask is int32 per element (bool promoted by harness): 64 ints per chain.
  if (tid < CPB) {
    int c = blk * CPB + tid;
    const int4* mp = (const int4*)(mask + (size_t)c * LPOS);
    unsigned long long m64 = 0;
    #pragma unroll
    for (int q = 0; q < 16; q++) {
      int4 mm = mp[q];
      unsigned long long b = (mm.x != 0 ? 1ull : 0ull) | (mm.y != 0 ? 2ull : 0ull) |
                             (mm.z != 0 ? 4ull : 0ull) | (mm.w != 0 ? 8ull : 0ull);
      m64 |= b << (q * 4);
    }
    const float* base = v + (size_t)batch_idx[c] * (LPOS * DV);
    #pragma unroll
    for (int s = 0; s < 8; s++) {
      const float* p;
      if (m64) {
        int pos = __ffsll(m64) - 1;
        m64 &= (m64 - 1);
        p = base + pos * DV;
      } else {
        p = zr;
      }
      s_ptr[tid][s] = p;
    }
    s_logc[tid] = log1pf((float)count[c]);
  }
  __syncthreads();

  // ---- Phase 1: gather X[32][1024] into LDS as bf16 ----
  {
    const int chain = tid >> 3, l8 = tid & 7;   // 8 threads per chain
    #pragma unroll
    for (int s = 0; s < 8; s++) {
      const float4* p = (const float4*)s_ptr[chain][s];
      #pragma unroll
      for (int part = 0; part < 4; part++) {
        int f4 = part * 8 + l8;                 // 0..31 float4s in this slot row
        float4 vv = p[f4];
        unsigned lo = pk2_bf16(vv.x, vv.y);
        unsigned hi = pk2_bf16(vv.z, vv.w);
        *(uint2*)&s_X[chain][s * DV + f4 * 4] = make_uint2(lo, hi);
      }
    }
  }
  __syncthreads();

  // ---- Phase 2: GEMM1  H = gelu(X @ W1 + b1 + logc*W1[1024,:]) ----
  const int l = tid & 63, w = tid >> 6;
  const int m = l & 15, kq = l >> 4;
  const int n0 = (2 * w) * 16 + m;   // this lane's column for nt=0
  const int n1 = n0 + 16;            // nt=1

  f32x4 acc00 = {0.f, 0.f, 0.f, 0.f}, acc01 = {0.f, 0.f, 0.f, 0.f};
  f32x4 acc10 = {0.f, 0.f, 0.f, 0.f}, acc11 = {0.f, 0.f, 0.f, 0.f};

  const unsigned short* bb0 = W1t + (size_t)n0 * KDIM + kq * 8;
  const unsigned short* bb1 = W1t + (size_t)n1 * KDIM + kq * 8;

  #pragma unroll 4
  for (int ch = 0; ch < 32; ch++) {
    int k0 = ch * 32 + kq * 8;
    bf16x8 a0 = *(const bf16x8*)&s_X[m][k0];
    bf16x8 a1 = *(const bf16x8*)&s_X[m + 16][k0];
    bf16x8 bf0 = *(const bf16x8*)(bb0 + ch * 32);
    bf16x8 bf1 = *(const bf16x8*)(bb1 + ch * 32);
    acc00 = __builtin_amdgcn_mfma_f32_16x16x32_bf16(a0, bf0, acc00, 0, 0, 0);
    acc01 = __builtin_amdgcn_mfma_f32_16x16x32_bf16(a0, bf1, acc01, 0, 0, 0);
    acc10 = __builtin_amdgcn_mfma_f32_16x16x32_bf16(a1, bf0, acc10, 0, 0, 0);
    acc11 = __builtin_amdgcn_mfma_f32_16x16x32_bf16(a1, bf1, acc11, 0, 0, 0);
  }

  // epilogue 1: rank-1 log_count term + bias + exact gelu, write H (bf16) to LDS
  {
    float w1l0 = W1[KDIM * HID + n0];
    float w1l1 = W1[KDIM * HID + n1];
    float b10 = b1[n0], b11 = b1[n1];
    #pragma unroll
    for (int r = 0; r < 4; r++) {
      int row = kq * 4 + r;            // C/D layout: row=(lane>>4)*4+reg, col=lane&15
      float lc0 = s_logc[row], lc1 = s_logc[16 + row];
      float h;
      h = acc00[r] + lc0 * w1l0 + b10; s_H[row][n0]      = cvt_bf16(gelu_exact(h));
      h = acc01[r] + lc0 * w1l1 + b11; s_H[row][n1]      = cvt_bf16(gelu_exact(h));
      h = acc10[r] + lc1 * w1l0 + b10; s_H[16 + row][n0] = cvt_bf16(gelu_exact(h));
      h = acc11[r] + lc1 * w1l1 + b11; s_H[16 + row][n1] = cvt_bf16(gelu_exact(h));
    }
  }
  __syncthreads();

  // ---- Phase 3: GEMM2  out = H @ W2 + b2 ----
  f32x4 d00 = {0.f, 0.f, 0.f, 0.f}, d01 = {0.f, 0.f, 0.f, 0.f};
  f32x4 d10 = {0.f, 0.f, 0.f, 0.f}, d11 = {0.f, 0.f, 0.f, 0.f};
  const unsigned short* cb0 = W2t + n0 * HID + kq * 8;
  const unsigned short* cb1 = W2t + n1 * HID + kq * 8;

  #pragma unroll
  for (int ch = 0; ch < 4; ch++) {
    int k0 = ch * 32 + kq * 8;
    bf16x8 a0 = *(const bf16x8*)&s_H[m][k0];
    bf16x8 a1 = *(const bf16x8*)&s_H[m + 16][k0];
    bf16x8 bf0 = *(const bf16x8*)(cb0 + ch * 32);
    bf16x8 bf1 = *(const bf16x8*)(cb1 + ch * 32);
    d00 = __builtin_amdgcn_mfma_f32_16x16x32_bf16(a0, bf0, d00, 0, 0, 0);
    d01 = __builtin_amdgcn_mfma_f32_16x16x32_bf16(a0, bf1, d01, 0, 0, 0);
    d10 = __builtin_amdgcn_mfma_f32_16x16x32_bf16(a1, bf0, d10, 0, 0, 0);
    d11 = __builtin_amdgcn_mfma_f32_16x16x32_bf16(a1, bf1, d11, 0, 0, 0);
  }

  {
    float b20 = b2[n0], b21 = b2[n1];
    #pragma unroll
    for (int r = 0; r < 4; r++) {
      int row = kq * 4 + r;
      size_t c0 = (size_t)(blk * CPB + row) * DV;
      size_t c1 = (size_t)(blk * CPB + 16 + row) * DV;
      out[c0 + n0] = d00[r] + b20;
      out[c0 + n1] = d01[r] + b21;
      out[c1 + n0] = d10[r] + b20;
      out[c1 + n1] = d11[r] + b21;
    }
  }
}

extern "C" void kernel_launch(void* const* d_in, const int* in_sizes, int n_in,
                              void* d_out, int out_size, void* d_ws, size_t ws_size,
                              hipStream_t stream) {
  const float* v          = (const float*)d_in[0];
  const int* batch_idx    = (const int*)d_in[1];
  const int* mk           = (const int*)d_in[2];
  const int* count        = (const int*)d_in[3];
  const float* W1         = (const float*)d_in[4];
  const float* b1         = (const float*)d_in[5];
  const float* W2         = (const float*)d_in[6];
  const float* b2         = (const float*)d_in[7];
  float* out              = (float*)d_out;

  char* ws = (char*)d_ws;
  unsigned short* W1t = (unsigned short*)ws;                       // 128*1024*2 = 262144 B
  unsigned short* W2t = (unsigned short*)(ws + 262144);            // 128*128*2  = 32768 B
  float* zr           = (float*)(ws + 262144 + 32768);             // 128*4      = 512 B

  prep_kernel<<<512, 256, 0, stream>>>(W1, W2, W1t, W2t, zr);
  agg_mlp_kernel<<<NCHAINS / CPB, 256, 0, stream>>>(
      v, batch_idx, mk, count, W1, b1, W2, b2, W1t, W2t, zr, out);
}

// Round 3
// 390.496 us; speedup vs baseline: 1.0112x; 1.0112x over previous
//
#include <hip/hip_runtime.h>
#include <hip/hip_bf16.h>
#include <math.h>

// ConcatMLPAggregator: gather-top8 + concat + MLP(1025->128 gelu ->128), bf16 MFMA.
// R3: no LDS staging of X — per-lane direct global A-fragment loads (occupancy
// 2->4 blocks/CU, gather overlapped with MFMA); W1/W2 pre-packed in MFMA
// fragment order for fully-coalesced B loads.
//
// Inputs:
//  d_in[0] v         [8192,64,128] fp32
//  d_in[1] batch_idx [32768] int32
//  d_in[2] mask      [32768,64] bool -> int32 on device
//  d_in[3] count     [32768] int32
//  d_in[4] W1        [1025,128] fp32
//  d_in[5] b1        [128] fp32
//  d_in[6] W2        [128,128] fp32
//  d_in[7] b2        [128] fp32
// Output: [32768,128] fp32

typedef __attribute__((ext_vector_type(8))) short bf16x8;
typedef __attribute__((ext_vector_type(4))) float f32x4;

#define NCHAINS 32768
#define LPOS    64
#define DV      128
#define HID     128
#define KDIM    1024   // 8 slots * 128
#define CPB     32     // chains per block

// round-to-nearest-even f32 -> bf16
__device__ __forceinline__ unsigned short cvt_bf16(float a) {
  unsigned u = __float_as_uint(a);
  u += 0x7fffu + ((u >> 16) & 1u);
  return (unsigned short)(u >> 16);
}
__device__ __forceinline__ unsigned pk2_bf16(float a, float b) {
  unsigned ua = __float_as_uint(a), ub = __float_as_uint(b);
  ua += 0x7fffu + ((ua >> 16) & 1u);
  ub += 0x7fffu + ((ub >> 16) & 1u);
  return (ua >> 16) | (ub & 0xffff0000u);
}
__device__ __forceinline__ bf16x8 pack8(float4 a, float4 b) {
  union { bf16x8 v; unsigned u[4]; } r;
  r.u[0] = pk2_bf16(a.x, a.y);
  r.u[1] = pk2_bf16(a.z, a.w);
  r.u[2] = pk2_bf16(b.x, b.y);
  r.u[3] = pk2_bf16(b.z, b.w);
  return r.v;
}
__device__ __forceinline__ float gelu_exact(float x) {
  return 0.5f * x * (1.0f + erff(x * 0.70710678118654752f));
}

// Prep: pack W1 (k<1024) and W2 into MFMA B-fragment order:
//   Wp[((ch*8 + nt)*64 + lane)*8 + j] = bf16( W[k][n] )
//   with k = ch*32 + ((lane>>4)&3)*8 + j,  n = nt*16 + (lane&15)
// so a wave's per-(ch,nt) fragment load is one coalesced 1024B dwordx4.
__global__ __launch_bounds__(256) void prep_kernel(
    const float* __restrict__ W1, const float* __restrict__ W2,
    unsigned short* __restrict__ W1p, unsigned short* __restrict__ W2p,
    float* __restrict__ zr) {
  int id = blockIdx.x * 256 + threadIdx.x;   // grid covers 131072
  {
    int j = id & 7, lx = (id >> 3) & 63, nt = (id >> 9) & 7, ch = id >> 12;
    int k = ch * 32 + ((lx >> 4) & 3) * 8 + j;
    int n = nt * 16 + (lx & 15);
    W1p[id] = cvt_bf16(W1[k * HID + n]);
    if (id < 16384) {
      int ch2 = id >> 12;      // 0..3
      int k2 = ch2 * 32 + ((lx >> 4) & 3) * 8 + j;
      W2p[id] = cvt_bf16(W2[k2 * HID + n]);
    }
  }
  if (id < DV) zr[id] = 0.0f;
}

__global__ __launch_bounds__(256, 4) void agg_mlp_kernel(
    const float* __restrict__ v, const int* __restrict__ batch_idx,
    const int* __restrict__ mask, const int* __restrict__ count,
    const float* __restrict__ W1, const float* __restrict__ b1,
    const float* __restrict__ b2,
    const unsigned short* __restrict__ W1p, const unsigned short* __restrict__ W2p,
    const float* __restrict__ zr, float* __restrict__ out) {
  __shared__ const float* s_ptr[CPB][8];
  __shared__ float s_logc[CPB];
  __shared__ unsigned short s_H[CPB][HID + 8];    // stride 136 elems = 272 B

  const int tid = threadIdx.x;
  const int blk = blockIdx.x;

  // ---- Phase 0: per-chain first-8 set-element extraction -> row pointers ----
  if (tid < CPB) {
    int c = blk * CPB + tid;
    const int4* mp = (const int4*)(mask + (size_t)c * LPOS);
    unsigned long long m64 = 0;
    #pragma unroll
    for (int q = 0; q < 16; q++) {
      int4 mm = mp[q];
      unsigned long long b = (mm.x != 0 ? 1ull : 0ull) | (mm.y != 0 ? 2ull : 0ull) |
                             (mm.z != 0 ? 4ull : 0ull) | (mm.w != 0 ? 8ull : 0ull);
      m64 |= b << (q * 4);
    }
    const float* base = v + (size_t)batch_idx[c] * (LPOS * DV);
    #pragma unroll
    for (int s = 0; s < 8; s++) {
      const float* p;
      if (m64) {
        int pos = __ffsll(m64) - 1;
        m64 &= (m64 - 1);
        p = base + pos * DV;
      } else {
        p = zr;
      }
      s_ptr[tid][s] = p;
    }
    s_logc[tid] = log1pf((float)count[c]);
  }
  __syncthreads();

  // ---- Phase 1: GEMM1  H = gelu(X @ W1 + b1 + logc*W1[1024,:]) ----
  // A fragments loaded straight from global via row pointers (no LDS staging).
  const int l = tid & 63, w = tid >> 6;
  const int m = l & 15, kq = l >> 4;
  const int nt0 = 2 * w, nt1 = 2 * w + 1;
  const int n0 = nt0 * 16 + m, n1 = n0 + 16;

  f32x4 acc00 = {0.f, 0.f, 0.f, 0.f}, acc01 = {0.f, 0.f, 0.f, 0.f};
  f32x4 acc10 = {0.f, 0.f, 0.f, 0.f}, acc11 = {0.f, 0.f, 0.f, 0.f};

  for (int s = 0; s < 8; s++) {
    const float* pa0 = s_ptr[m][s] + kq * 8;
    const float* pa1 = s_ptr[m + 16][s] + kq * 8;
    #pragma unroll
    for (int q = 0; q < 4; q++) {
      const int off = q * 32;                 // immediate offsets within slot row
      float4 x0 = *(const float4*)(pa0 + off);
      float4 x1 = *(const float4*)(pa0 + off + 4);
      float4 y0 = *(const float4*)(pa1 + off);
      float4 y1 = *(const float4*)(pa1 + off + 4);
      const int ch = s * 4 + q;
      bf16x8 b0 = *(const bf16x8*)(W1p + (size_t)((ch * 8 + nt0) * 64 + l) * 8);
      bf16x8 b1 = *(const bf16x8*)(W1p + (size_t)((ch * 8 + nt1) * 64 + l) * 8);
      bf16x8 a0 = pack8(x0, x1);
      bf16x8 a1 = pack8(y0, y1);
      acc00 = __builtin_amdgcn_mfma_f32_16x16x32_bf16(a0, b0, acc00, 0, 0, 0);
      acc01 = __builtin_amdgcn_mfma_f32_16x16x32_bf16(a0, b1, acc01, 0, 0, 0);
      acc10 = __builtin_amdgcn_mfma_f32_16x16x32_bf16(a1, b0, acc10, 0, 0, 0);
      acc11 = __builtin_amdgcn_mfma_f32_16x16x32_bf16(a1, b1, acc11, 0, 0, 0);
    }
  }

  // epilogue 1: rank-1 log_count term + bias + exact gelu, write H (bf16) to LDS
  {
    float w1l0 = W1[KDIM * HID + n0];
    float w1l1 = W1[KDIM * HID + n1];
    float b10 = b1[n0], b11 = b1[n1];
    #pragma unroll
    for (int r = 0; r < 4; r++) {
      int row = kq * 4 + r;            // C/D layout: row=(lane>>4)*4+reg, col=lane&15
      float lc0 = s_logc[row], lc1 = s_logc[16 + row];
      float h;
      h = acc00[r] + lc0 * w1l0 + b10; s_H[row][n0]      = cvt_bf16(gelu_exact(h));
      h = acc01[r] + lc0 * w1l1 + b11; s_H[row][n1]      = cvt_bf16(gelu_exact(h));
      h = acc10[r] + lc1 * w1l0 + b10; s_H[16 + row][n0] = cvt_bf16(gelu_exact(h));
      h = acc11[r] + lc1 * w1l1 + b11; s_H[16 + row][n1] = cvt_bf16(gelu_exact(h));
    }
  }
  __syncthreads();

  // ---- Phase 2: GEMM2  out = H @ W2 + b2 ----
  f32x4 d00 = {0.f, 0.f, 0.f, 0.f}, d01 = {0.f, 0.f, 0.f, 0.f};
  f32x4 d10 = {0.f, 0.f, 0.f, 0.f}, d11 = {0.f, 0.f, 0.f, 0.f};

  #pragma unroll
  for (int ch = 0; ch < 4; ch++) {
    int k0 = ch * 32 + kq * 8;
    bf16x8 a0 = *(const bf16x8*)&s_H[m][k0];
    bf16x8 a1 = *(const bf16x8*)&s_H[m + 16][k0];
    bf16x8 b0 = *(const bf16x8*)(W2p + (size_t)((ch * 8 + nt0) * 64 + l) * 8);
    bf16x8 b1 = *(const bf16x8*)(W2p + (size_t)((ch * 8 + nt1) * 64 + l) * 8);
    d00 = __builtin_amdgcn_mfma_f32_16x16x32_bf16(a0, b0, d00, 0, 0, 0);
    d01 = __builtin_amdgcn_mfma_f32_16x16x32_bf16(a0, b1, d01, 0, 0, 0);
    d10 = __builtin_amdgcn_mfma_f32_16x16x32_bf16(a1, b0, d10, 0, 0, 0);
    d11 = __builtin_amdgcn_mfma_f32_16x16x32_bf16(a1, b1, d11, 0, 0, 0);
  }

  {
    float b20 = b2[n0], b21 = b2[n1];
    #pragma unroll
    for (int r = 0; r < 4; r++) {
      int row = kq * 4 + r;
      size_t c0 = (size_t)(blk * CPB + row) * DV;
      size_t c1 = (size_t)(blk * CPB + 16 + row) * DV;
      out[c0 + n0] = d00[r] + b20;
      out[c0 + n1] = d01[r] + b21;
      out[c1 + n0] = d10[r] + b20;
      out[c1 + n1] = d11[r] + b21;
    }
  }
}

extern "C" void kernel_launch(void* const* d_in, const int* in_sizes, int n_in,
                              void* d_out, int out_size, void* d_ws, size_t ws_size,
                              hipStream_t stream) {
  const float* v          = (const float*)d_in[0];
  const int* batch_idx    = (const int*)d_in[1];
  const int* mk           = (const int*)d_in[2];
  const int* count        = (const int*)d_in[3];
  const float* W1         = (const float*)d_in[4];
  const float* b1         = (const float*)d_in[5];
  const float* W2         = (const float*)d_in[6];
  const float* b2         = (const float*)d_in[7];
  float* out              = (float*)d_out;

  char* ws = (char*)d_ws;
  unsigned short* W1p = (unsigned short*)ws;                       // 128*1024*2 = 262144 B
  unsigned short* W2p = (unsigned short*)(ws + 262144);            // 128*128*2  = 32768 B
  float* zr           = (float*)(ws + 262144 + 32768);             // 128*4      = 512 B

  prep_kernel<<<512, 256, 0, stream>>>(W1, W2, W1p, W2p, zr);
  agg_mlp_kernel<<<NCHAINS / CPB, 256, 0, stream>>>(
      v, batch_idx, mk, count, W1, b1, b2, W1p, W2p, zr, out);
}

// Round 4
// 373.592 us; speedup vs baseline: 1.0569x; 1.0452x over previous
//
#include <hip/hip_runtime.h>
#include <hip/hip_bf16.h>
#include <math.h>

// ConcatMLPAggregator: gather-top8 + concat + MLP(1025->128 gelu ->128), bf16 MFMA.
// R4: per-wave tile split = (row-half x col-half) -> 1 A-fragment per K-step,
// ~90 VGPRs, launch_bounds(256,5) for 20 waves/CU; A-redundancy 4x->2x.
//
// Inputs:
//  d_in[0] v         [8192,64,128] fp32
//  d_in[1] batch_idx [32768] int32
//  d_in[2] mask      [32768,64] bool -> int32 on device
//  d_in[3] count     [32768] int32
//  d_in[4] W1        [1025,128] fp32
//  d_in[5] b1        [128] fp32
//  d_in[6] W2        [128,128] fp32
//  d_in[7] b2        [128] fp32
// Output: [32768,128] fp32

typedef __attribute__((ext_vector_type(8))) short bf16x8;
typedef __attribute__((ext_vector_type(4))) float f32x4;

#define NCHAINS 32768
#define LPOS    64
#define DV      128
#define HID     128
#define KDIM    1024   // 8 slots * 128
#define CPB     32     // chains per block

// round-to-nearest-even f32 -> bf16
__device__ __forceinline__ unsigned short cvt_bf16(float a) {
  unsigned u = __float_as_uint(a);
  u += 0x7fffu + ((u >> 16) & 1u);
  return (unsigned short)(u >> 16);
}
__device__ __forceinline__ unsigned pk2_bf16(float a, float b) {
  unsigned ua = __float_as_uint(a), ub = __float_as_uint(b);
  ua += 0x7fffu + ((ua >> 16) & 1u);
  ub += 0x7fffu + ((ub >> 16) & 1u);
  return (ua >> 16) | (ub & 0xffff0000u);
}
__device__ __forceinline__ bf16x8 pack8(float4 a, float4 b) {
  union { bf16x8 v; unsigned u[4]; } r;
  r.u[0] = pk2_bf16(a.x, a.y);
  r.u[1] = pk2_bf16(a.z, a.w);
  r.u[2] = pk2_bf16(b.x, b.y);
  r.u[3] = pk2_bf16(b.z, b.w);
  return r.v;
}
__device__ __forceinline__ float gelu_exact(float x) {
  return 0.5f * x * (1.0f + erff(x * 0.70710678118654752f));
}

// Prep: pack W1 (k<1024) and W2 into MFMA B-fragment order:
//   Wp[((ch*8 + nt)*64 + lane)*8 + j] = bf16( W[k][n] )
//   with k = ch*32 + ((lane>>4)&3)*8 + j,  n = nt*16 + (lane&15)
__global__ __launch_bounds__(256) void prep_kernel(
    const float* __restrict__ W1, const float* __restrict__ W2,
    unsigned short* __restrict__ W1p, unsigned short* __restrict__ W2p,
    float* __restrict__ zr) {
  int id = blockIdx.x * 256 + threadIdx.x;   // grid covers 131072
  {
    int j = id & 7, lx = (id >> 3) & 63, nt = (id >> 9) & 7, ch = id >> 12;
    int k = ch * 32 + ((lx >> 4) & 3) * 8 + j;
    int n = nt * 16 + (lx & 15);
    W1p[id] = cvt_bf16(W1[k * HID + n]);
    if (id < 16384) {
      int ch2 = id >> 12;      // 0..3
      int k2 = ch2 * 32 + ((lx >> 4) & 3) * 8 + j;
      W2p[id] = cvt_bf16(W2[k2 * HID + n]);
    }
  }
  if (id < DV) zr[id] = 0.0f;
}

__global__ __launch_bounds__(256, 5) void agg_mlp_kernel(
    const float* __restrict__ v, const int* __restrict__ batch_idx,
    const int* __restrict__ mask, const int* __restrict__ count,
    const float* __restrict__ W1, const float* __restrict__ b1,
    const float* __restrict__ b2,
    const unsigned short* __restrict__ W1p, const unsigned short* __restrict__ W2p,
    const float* __restrict__ zr, float* __restrict__ out) {
  __shared__ const float* s_ptr[CPB][8];
  __shared__ float s_logc[CPB];
  __shared__ unsigned short s_H[CPB][HID + 8];    // stride 136 elems = 272 B

  const int tid = threadIdx.x;
  const int blk = blockIdx.x;

  // ---- Phase 0: per-chain first-8 set-element extraction -> row pointers ----
  if (tid < CPB) {
    int c = blk * CPB + tid;
    const int4* mp = (const int4*)(mask + (size_t)c * LPOS);
    unsigned long long m64 = 0;
    #pragma unroll
    for (int q = 0; q < 16; q++) {
      int4 mm = mp[q];
      unsigned long long b = (mm.x != 0 ? 1ull : 0ull) | (mm.y != 0 ? 2ull : 0ull) |
                             (mm.z != 0 ? 4ull : 0ull) | (mm.w != 0 ? 8ull : 0ull);
      m64 |= b << (q * 4);
    }
    const float* base = v + (size_t)batch_idx[c] * (LPOS * DV);
    #pragma unroll
    for (int s = 0; s < 8; s++) {
      const float* p;
      if (m64) {
        int pos = __ffsll(m64) - 1;
        m64 &= (m64 - 1);
        p = base + pos * DV;
      } else {
        p = zr;
      }
      s_ptr[tid][s] = p;
    }
    s_logc[tid] = log1pf((float)count[c]);
  }
  __syncthreads();

  // ---- Phase 1: GEMM1  H = gelu(X @ W1 + b1 + logc*W1[1024,:]) ----
  // Wave w: row-half mh = w&1 (chains mh*16..mh*16+15),
  //         col-half cb = w>>1 (cols cb*64 .. cb*64+63, i.e. nt = cb*4 + 0..3).
  const int l = tid & 63, w = tid >> 6;
  const int mh = w & 1, cb = w >> 1;
  const int m = l & 15, kq = l >> 4;          // A row (within half) / k-quad
  const int chain = mh * 16 + m;              // chain this lane's A-loads serve

  f32x4 acc0 = {0.f,0.f,0.f,0.f}, acc1 = {0.f,0.f,0.f,0.f};
  f32x4 acc2 = {0.f,0.f,0.f,0.f}, acc3 = {0.f,0.f,0.f,0.f};

  #pragma unroll 2
  for (int ch = 0; ch < 32; ch++) {
    const int s = ch >> 2, q = ch & 3;
    const float* pa = s_ptr[chain][s] + q * 32 + kq * 8;
    float4 x0 = *(const float4*)pa;
    float4 x1 = *(const float4*)(pa + 4);
    const unsigned short* wb = W1p + ((size_t)(ch * 8 + cb * 4) * 64 + l) * 8;
    bf16x8 b0 = *(const bf16x8*)(wb);
    bf16x8 b1f = *(const bf16x8*)(wb + 512);
    bf16x8 b2f = *(const bf16x8*)(wb + 1024);
    bf16x8 b3f = *(const bf16x8*)(wb + 1536);
    bf16x8 a = pack8(x0, x1);
    acc0 = __builtin_amdgcn_mfma_f32_16x16x32_bf16(a, b0,  acc0, 0, 0, 0);
    acc1 = __builtin_amdgcn_mfma_f32_16x16x32_bf16(a, b1f, acc1, 0, 0, 0);
    acc2 = __builtin_amdgcn_mfma_f32_16x16x32_bf16(a, b2f, acc2, 0, 0, 0);
    acc3 = __builtin_amdgcn_mfma_f32_16x16x32_bf16(a, b3f, acc3, 0, 0, 0);
  }

  // epilogue 1: rank-1 log_count term + bias + exact gelu, write H (bf16) to LDS
  {
    float w1l[4], b1v[4];
    #pragma unroll
    for (int nt = 0; nt < 4; nt++) {
      int n = cb * 64 + nt * 16 + m;
      w1l[nt] = W1[KDIM * HID + n];
      b1v[nt] = b1[n];
    }
    f32x4* accs[4] = {&acc0, &acc1, &acc2, &acc3};
    #pragma unroll
    for (int r = 0; r < 4; r++) {
      int row = mh * 16 + kq * 4 + r;   // C/D: row=(lane>>4)*4+reg, col=lane&15
      float lc = s_logc[row];
      #pragma unroll
      for (int nt = 0; nt < 4; nt++) {
        float h = (*accs[nt])[r] + lc * w1l[nt] + b1v[nt];
        s_H[row][cb * 64 + nt * 16 + m] = cvt_bf16(gelu_exact(h));
      }
    }
  }
  __syncthreads();

  // ---- Phase 2: GEMM2  out = H @ W2 + b2 ----
  f32x4 d0 = {0.f,0.f,0.f,0.f}, d1 = {0.f,0.f,0.f,0.f};
  f32x4 d2 = {0.f,0.f,0.f,0.f}, d3 = {0.f,0.f,0.f,0.f};

  #pragma unroll
  for (int ch = 0; ch < 4; ch++) {
    bf16x8 a = *(const bf16x8*)&s_H[mh * 16 + m][ch * 32 + kq * 8];
    const unsigned short* wb = W2p + ((size_t)(ch * 8 + cb * 4) * 64 + l) * 8;
    bf16x8 b0 = *(const bf16x8*)(wb);
    bf16x8 b1f = *(const bf16x8*)(wb + 512);
    bf16x8 b2f = *(const bf16x8*)(wb + 1024);
    bf16x8 b3f = *(const bf16x8*)(wb + 1536);
    d0 = __builtin_amdgcn_mfma_f32_16x16x32_bf16(a, b0,  d0, 0, 0, 0);
    d1 = __builtin_amdgcn_mfma_f32_16x16x32_bf16(a, b1f, d1, 0, 0, 0);
    d2 = __builtin_amdgcn_mfma_f32_16x16x32_bf16(a, b2f, d2, 0, 0, 0);
    d3 = __builtin_amdgcn_mfma_f32_16x16x32_bf16(a, b3f, d3, 0, 0, 0);
  }

  {
    float b2v[4];
    #pragma unroll
    for (int nt = 0; nt < 4; nt++) b2v[nt] = b2[cb * 64 + nt * 16 + m];
    f32x4* ds[4] = {&d0, &d1, &d2, &d3};
    #pragma unroll
    for (int r = 0; r < 4; r++) {
      int row = mh * 16 + kq * 4 + r;
      size_t o = (size_t)(blk * CPB + row) * DV;
      #pragma unroll
      for (int nt = 0; nt < 4; nt++) {
        out[o + cb * 64 + nt * 16 + m] = (*ds[nt])[r] + b2v[nt];
      }
    }
  }
}

extern "C" void kernel_launch(void* const* d_in, const int* in_sizes, int n_in,
                              void* d_out, int out_size, void* d_ws, size_t ws_size,
                              hipStream_t stream) {
  const float* v          = (const float*)d_in[0];
  const int* batch_idx    = (const int*)d_in[1];
  const int* mk           = (const int*)d_in[2];
  const int* count        = (const int*)d_in[3];
  const float* W1         = (const float*)d_in[4];
  const float* b1         = (const float*)d_in[5];
  const float* W2         = (const float*)d_in[6];
  const float* b2         = (const float*)d_in[7];
  float* out              = (float*)d_out;

  char* ws = (char*)d_ws;
  unsigned short* W1p = (unsigned short*)ws;                       // 128*1024*2 = 262144 B
  unsigned short* W2p = (unsigned short*)(ws + 262144);            // 128*128*2  = 32768 B
  float* zr           = (float*)(ws + 262144 + 32768);             // 128*4      = 512 B

  prep_kernel<<<512, 256, 0, stream>>>(W1, W2, W1p, W2p, zr);
  agg_mlp_kernel<<<NCHAINS / CPB, 256, 0, stream>>>(
      v, batch_idx, mk, count, W1, b1, b2, W1p, W2p, zr, out);
}

// Round 5
// 373.567 us; speedup vs baseline: 1.0570x; 1.0001x over previous
//
#include <hip/hip_runtime.h>
#include <hip/hip_bf16.h>
#include <math.h>

// ConcatMLPAggregator R5: split design.
//  prep:        pack W1/W2 to bf16 MFMA-B-fragment order; zero row.
//  gather_pack: mask decode + gather v rows, write X in MFMA-A-fragment order
//               (scattered-but-local reads, fully coalesced writes).
//  gemm:        pure streaming MFMA kernel, all loads coalesced.
//
// Xp layout: Xp[((ht*32 + ch)*64 + lam)*8 + j] = bf16(X[c][k])
//   ht = c>>4, m = c&15, lam = m + 16*kq, k = ch*32 + kq*8 + j.

typedef __attribute__((ext_vector_type(8))) short bf16x8;
typedef __attribute__((ext_vector_type(4))) float f32x4;

#define NCHAINS 32768
#define LPOS    64
#define DV      128
#define HID     128
#define KDIM    1024
#define CPB     32

__device__ __forceinline__ unsigned short cvt_bf16(float a) {
  unsigned u = __float_as_uint(a);
  u += 0x7fffu + ((u >> 16) & 1u);
  return (unsigned short)(u >> 16);
}
__device__ __forceinline__ unsigned pk2_bf16(float a, float b) {
  unsigned ua = __float_as_uint(a), ub = __float_as_uint(b);
  ua += 0x7fffu + ((ua >> 16) & 1u);
  ub += 0x7fffu + ((ub >> 16) & 1u);
  return (ua >> 16) | (ub & 0xffff0000u);
}
__device__ __forceinline__ float gelu_exact(float x) {
  return 0.5f * x * (1.0f + erff(x * 0.70710678118654752f));
}

// Wp[((ch*8 + nt)*64 + lane)*8 + j] = bf16(W[k][n]), k=ch*32+((lane>>4)&3)*8+j, n=nt*16+(lane&15)
__global__ __launch_bounds__(256) void prep_kernel(
    const float* __restrict__ W1, const float* __restrict__ W2,
    unsigned short* __restrict__ W1p, unsigned short* __restrict__ W2p,
    float* __restrict__ zr) {
  int id = blockIdx.x * 256 + threadIdx.x;   // 131072 total
  {
    int j = id & 7, lx = (id >> 3) & 63, nt = (id >> 9) & 7, ch = id >> 12;
    int k = ch * 32 + ((lx >> 4) & 3) * 8 + j;
    int n = nt * 16 + (lx & 15);
    W1p[id] = cvt_bf16(W1[k * HID + n]);
    if (id < 16384) {
      int ch2 = id >> 12;
      int k2 = ch2 * 32 + ((lx >> 4) & 3) * 8 + j;
      W2p[id] = cvt_bf16(W2[k2 * HID + n]);
    }
  }
  if (id < DV) zr[id] = 0.0f;
}

// Block = one half-tile ht (16 chains). 2048 blocks x 256 threads.
__global__ __launch_bounds__(256, 8) void gather_pack_kernel(
    const float* __restrict__ v, const int* __restrict__ batch_idx,
    const int* __restrict__ mask,
    const float* __restrict__ zr, unsigned short* __restrict__ Xp) {
  __shared__ const float* s_rp[16][8];

  const int tid = threadIdx.x;
  const int ht = blockIdx.x;

  if (tid < 16) {
    int c = ht * 16 + tid;
    const int4* mp = (const int4*)(mask + (size_t)c * LPOS);
    unsigned long long m64 = 0;
    #pragma unroll
    for (int q = 0; q < 16; q++) {
      int4 mm = mp[q];
      unsigned long long b = (mm.x != 0 ? 1ull : 0ull) | (mm.y != 0 ? 2ull : 0ull) |
                             (mm.z != 0 ? 4ull : 0ull) | (mm.w != 0 ? 8ull : 0ull);
      m64 |= b << (q * 4);
    }
    const float* base = v + (size_t)batch_idx[c] * (LPOS * DV);
    #pragma unroll
    for (int s = 0; s < 8; s++) {
      const float* p;
      if (m64) {
        int pos = __ffsll(m64) - 1;
        m64 &= (m64 - 1);
        p = base + pos * DV;
      } else {
        p = zr;
      }
      s_rp[tid][s] = p;
    }
  }
  __syncthreads();

  const int w = tid >> 6, l = tid & 63;
  const int m = l >> 2, kq = l & 3;           // read-adjacent lane permutation
  const int g = w * 64 + ((l >> 2) | ((l & 3) << 4));   // Xp group = w*64 + (m + 16*kq)
  const int koff = w * 32 + kq * 8;           // float offset within source row

  // preload this thread's 8 row pointers
  const float* p[8];
  #pragma unroll
  for (int s = 0; s < 8; s++) p[s] = s_rp[m][s];

  uint4* dst = (uint4*)(Xp + (size_t)ht * 16384) + g;   // 16B per group

  #pragma unroll
  for (int i = 0; i < 8; i++) {               // iter i covers ch = i*4 + w, s = i
    const float* src = p[i] + koff;
    float4 x0 = *(const float4*)src;
    float4 x1 = *(const float4*)(src + 4);
    uint4 o;
    o.x = pk2_bf16(x0.x, x0.y);
    o.y = pk2_bf16(x0.z, x0.w);
    o.z = pk2_bf16(x1.x, x1.y);
    o.w = pk2_bf16(x1.z, x1.w);
    dst[i * 256] = o;                         // i*2048 elems = i*256 uint4s
  }
}

// Block = 32 chains (half-tiles 2b, 2b+1). 1024 blocks x 256 threads.
__global__ __launch_bounds__(256, 4) void gemm_kernel(
    const int* __restrict__ count,
    const float* __restrict__ W1, const float* __restrict__ b1,
    const float* __restrict__ b2,
    const unsigned short* __restrict__ W1p, const unsigned short* __restrict__ W2p,
    const unsigned short* __restrict__ Xp, float* __restrict__ out) {
  __shared__ float s_logc[CPB];
  __shared__ unsigned short s_H[CPB][HID + 8];

  const int tid = threadIdx.x;
  const int blk = blockIdx.x;

  if (tid < CPB) s_logc[tid] = log1pf((float)count[blk * CPB + tid]);
  __syncthreads();

  const int l = tid & 63, w = tid >> 6;
  const int mh = w & 1, cb = w >> 1;
  const int m = l & 15, kq = l >> 4;

  const unsigned short* ap = Xp + (size_t)(2 * blk + mh) * 16384 + l * 8;
  const unsigned short* bp = W1p + ((size_t)(cb * 4) * 64 + l) * 8;

  f32x4 acc0 = {0.f,0.f,0.f,0.f}, acc1 = {0.f,0.f,0.f,0.f};
  f32x4 acc2 = {0.f,0.f,0.f,0.f}, acc3 = {0.f,0.f,0.f,0.f};

  #pragma unroll 2
  for (int ch = 0; ch < 32; ch++) {
    bf16x8 a = *(const bf16x8*)(ap + (size_t)ch * 512);
    const unsigned short* wb = bp + (size_t)ch * 4096;
    bf16x8 b0 = *(const bf16x8*)(wb);
    bf16x8 b1f = *(const bf16x8*)(wb + 512);
    bf16x8 b2f = *(const bf16x8*)(wb + 1024);
    bf16x8 b3f = *(const bf16x8*)(wb + 1536);
    acc0 = __builtin_amdgcn_mfma_f32_16x16x32_bf16(a, b0,  acc0, 0, 0, 0);
    acc1 = __builtin_amdgcn_mfma_f32_16x16x32_bf16(a, b1f, acc1, 0, 0, 0);
    acc2 = __builtin_amdgcn_mfma_f32_16x16x32_bf16(a, b2f, acc2, 0, 0, 0);
    acc3 = __builtin_amdgcn_mfma_f32_16x16x32_bf16(a, b3f, acc3, 0, 0, 0);
  }

  {
    float w1l[4], b1v[4];
    #pragma unroll
    for (int nt = 0; nt < 4; nt++) {
      int n = cb * 64 + nt * 16 + m;
      w1l[nt] = W1[KDIM * HID + n];
      b1v[nt] = b1[n];
    }
    f32x4* accs[4] = {&acc0, &acc1, &acc2, &acc3};
    #pragma unroll
    for (int r = 0; r < 4; r++) {
      int row = mh * 16 + kq * 4 + r;   // C/D: row=(lane>>4)*4+reg, col=lane&15
      float lc = s_logc[row];
      #pragma unroll
      for (int nt = 0; nt < 4; nt++) {
        float h = (*accs[nt])[r] + lc * w1l[nt] + b1v[nt];
        s_H[row][cb * 64 + nt * 16 + m] = cvt_bf16(gelu_exact(h));
      }
    }
  }
  __syncthreads();

  f32x4 d0 = {0.f,0.f,0.f,0.f}, d1 = {0.f,0.f,0.f,0.f};
  f32x4 d2 = {0.f,0.f,0.f,0.f}, d3 = {0.f,0.f,0.f,0.f};

  #pragma unroll
  for (int ch = 0; ch < 4; ch++) {
    bf16x8 a = *(const bf16x8*)&s_H[mh * 16 + m][ch * 32 + kq * 8];
    const unsigned short* wb = W2p + ((size_t)(ch * 8 + cb * 4) * 64 + l) * 8;
    bf16x8 b0 = *(const bf16x8*)(wb);
    bf16x8 b1f = *(const bf16x8*)(wb + 512);
    bf16x8 b2f = *(const bf16x8*)(wb + 1024);
    bf16x8 b3f = *(const bf16x8*)(wb + 1536);
    d0 = __builtin_amdgcn_mfma_f32_16x16x32_bf16(a, b0,  d0, 0, 0, 0);
    d1 = __builtin_amdgcn_mfma_f32_16x16x32_bf16(a, b1f, d1, 0, 0, 0);
    d2 = __builtin_amdgcn_mfma_f32_16x16x32_bf16(a, b2f, d2, 0, 0, 0);
    d3 = __builtin_amdgcn_mfma_f32_16x16x32_bf16(a, b3f, d3, 0, 0, 0);
  }

  {
    float b2v[4];
    #pragma unroll
    for (int nt = 0; nt < 4; nt++) b2v[nt] = b2[cb * 64 + nt * 16 + m];
    f32x4* ds[4] = {&d0, &d1, &d2, &d3};
    #pragma unroll
    for (int r = 0; r < 4; r++) {
      int row = mh * 16 + kq * 4 + r;
      size_t o = (size_t)(blk * CPB + row) * DV;
      #pragma unroll
      for (int nt = 0; nt < 4; nt++) {
        out[o + cb * 64 + nt * 16 + m] = (*ds[nt])[r] + b2v[nt];
      }
    }
  }
}

extern "C" void kernel_launch(void* const* d_in, const int* in_sizes, int n_in,
                              void* d_out, int out_size, void* d_ws, size_t ws_size,
                              hipStream_t stream) {
  const float* v          = (const float*)d_in[0];
  const int* batch_idx    = (const int*)d_in[1];
  const int* mk           = (const int*)d_in[2];
  const int* count        = (const int*)d_in[3];
  const float* W1         = (const float*)d_in[4];
  const float* b1         = (const float*)d_in[5];
  const float* W2         = (const float*)d_in[6];
  const float* b2         = (const float*)d_in[7];
  float* out              = (float*)d_out;

  char* ws = (char*)d_ws;
  unsigned short* W1p = (unsigned short*)ws;                       // 262144 B
  unsigned short* W2p = (unsigned short*)(ws + 262144);            // 32768 B
  float* zr           = (float*)(ws + 262144 + 32768);             // 512 B
  unsigned short* Xp  = (unsigned short*)(ws + 262144 + 32768 + 512); // 64 MiB, 16B-aligned

  prep_kernel<<<512, 256, 0, stream>>>(W1, W2, W1p, W2p, zr);
  gather_pack_kernel<<<NCHAINS / 16, 256, 0, stream>>>(v, batch_idx, mk, zr, Xp);
  gemm_kernel<<<NCHAINS / CPB, 256, 0, stream>>>(
      count, W1, b1, b2, W1p, W2p, Xp, out);
}